// Round 1
// baseline (451.774 us; speedup 1.0000x reference)
//
#include <hip/hip_runtime.h>

#define NTOK 64
#define DIM 256
#define SCALE 0.17677669529663687f

typedef __attribute__((ext_vector_type(8))) short short8;
typedef __attribute__((ext_vector_type(4))) float f32x4;

__device__ __forceinline__ unsigned short f2bf(float f) {
  unsigned u = __float_as_uint(f);
  u += 0x7fffu + ((u >> 16) & 1u);
  return (unsigned short)(u >> 16);
}

__device__ __forceinline__ unsigned long long pack4(float a, float b, float c, float d) {
  unsigned lo = (unsigned)f2bf(a) | ((unsigned)f2bf(b) << 16);
  unsigned hi = (unsigned)f2bf(c) | ((unsigned)f2bf(d) << 16);
  return (unsigned long long)lo | ((unsigned long long)hi << 32);
}

// ---- Prologue 1: weights fp32 -> bf16 (qkv_w 768x256, proj_w 256x256)
__global__ void cvt_weights_kernel(const float* __restrict__ qkv_w,
                                   const float* __restrict__ proj_w,
                                   unsigned short* __restrict__ qkv_wb,
                                   unsigned short* __restrict__ proj_wb) {
  int idx = blockIdx.x * 256 + threadIdx.x;   // grid covers 196608+65536 exactly
  if (idx < 196608) {
    qkv_wb[idx] = f2bf(qkv_w[idx]);
  } else {
    int p = idx - 196608;
    proj_wb[p] = f2bf(proj_w[p]);
  }
}

// ---- Prologue 2: rpe[h][i][j] = rpb_table[rel_pos_index[i][j]][h]  (fp32, 8x64x64)
__global__ void build_rpe_kernel(const float* __restrict__ table,
                                 const int* __restrict__ rel,
                                 float* __restrict__ rpe) {
  int idx = blockIdx.x * 256 + threadIdx.x;   // 32768 total
  int h = idx >> 12;
  int ij = idx & 4095;
  rpe[idx] = table[rel[ij] * 8 + h];
}

// ---- Main fused kernel: one block per window, 8 waves = 8 heads.
// LDS (ushort elems):
//   x/O buf : [64][264]              -> 16896      (x bf16; later reused for attn-out)
//   per wave w (base 16896 + w*7424):
//     qS [64][40] (2560) | kS [64][40] (2560) | vS(T) [32][72] (2304)
//     pS [64][72] (4608) aliases qS+kS after S is computed
// total 76288 ushort = 152576 B -> 1 block/CU
__global__ __launch_bounds__(512)
void win_attn_kernel(const float* __restrict__ x,
                     const float* __restrict__ mask,
                     const unsigned short* __restrict__ qkv_wb,
                     const float* __restrict__ qkv_b,
                     const unsigned short* __restrict__ proj_wb,
                     const float* __restrict__ proj_b,
                     const float* __restrict__ rpe,
                     float* __restrict__ out) {
  __shared__ unsigned short lds[76288];
  const int bid  = blockIdx.x;
  const int tid  = threadIdx.x;
  const int w    = tid >> 6;     // wave = head
  const int lane = tid & 63;
  const int lr   = lane & 15;
  const int lg   = lane >> 4;

  // ---- Phase 1: stage x -> LDS bf16 [64][264] (fully coalesced float4 loads)
  {
    const f32x4* xg = (const f32x4*)(x + (size_t)bid * (NTOK * DIM));
#pragma unroll
    for (int i = 0; i < 8; ++i) {
      int vi = i * 512 + tid;               // float4 index, 4096 total
      f32x4 v = xg[vi];
      int fe = vi * 4;
      int row = fe >> 8;
      int col = fe & 255;
      *(unsigned long long*)&lds[row * 264 + col] = pack4(v[0], v[1], v[2], v[3]);
    }
  }
  __syncthreads();   // B0: x staged

  unsigned short* wbase = &lds[16896 + w * 7424];
  unsigned short* qS = wbase;          // [64][40]
  unsigned short* kS = wbase + 2560;   // [64][40]
  unsigned short* vS = wbase + 5120;   // vT [32][72]
  unsigned short* pS = wbase;          // P [64][72], aliases qS+kS (dead by then)

  // ---- Phase 2: q,k,v = x @ Wqkv_head^T  (3 x [64x256 @ 256x32] MFMA)
#pragma unroll
  for (int o = 0; o < 3; ++o) {
    const int wrow0 = o * 256 + w * 32;
    f32x4 acc[4][2];
#pragma unroll
    for (int mt = 0; mt < 4; ++mt)
#pragma unroll
      for (int nt = 0; nt < 2; ++nt)
        acc[mt][nt] = (f32x4){0.f, 0.f, 0.f, 0.f};
#pragma unroll
    for (int ks = 0; ks < 8; ++ks) {
      short8 a[4], b[2];
#pragma unroll
      for (int mt = 0; mt < 4; ++mt)
        a[mt] = *(const short8*)&lds[(mt * 16 + lr) * 264 + ks * 32 + lg * 8];
#pragma unroll
      for (int nt = 0; nt < 2; ++nt)
        b[nt] = *(const short8*)&qkv_wb[(wrow0 + nt * 16 + lr) * 256 + ks * 32 + lg * 8];
#pragma unroll
      for (int mt = 0; mt < 4; ++mt)
#pragma unroll
        for (int nt = 0; nt < 2; ++nt)
          acc[mt][nt] = __builtin_amdgcn_mfma_f32_16x16x32_bf16(a[mt], b[nt], acc[mt][nt], 0, 0, 0);
    }
    // epilogue: +bias, (q also *SCALE), write staging
#pragma unroll
    for (int nt = 0; nt < 2; ++nt) {
      float bias = qkv_b[wrow0 + nt * 16 + lr];
#pragma unroll
      for (int mt = 0; mt < 4; ++mt)
#pragma unroll
        for (int r = 0; r < 4; ++r) {
          int tok = mt * 16 + lg * 4 + r;
          int d   = nt * 16 + lr;
          float val = acc[mt][nt][r] + bias;
          if (o == 0)      qS[tok * 40 + d] = f2bf(val * SCALE);
          else if (o == 1) kS[tok * 40 + d] = f2bf(val);
          else             vS[d * 72 + tok] = f2bf(val);   // store v transposed
        }
    }
  }
  __syncthreads();   // B1: all waves done reading x (x-buf now dead)

  // ---- Phase 3: S = q @ k^T (single K-step!), +rpe +mask, softmax -> P (bf16, LDS)
  f32x4 s[4][4];
  {
    short8 qa[4], kb[4];
#pragma unroll
    for (int mt = 0; mt < 4; ++mt)
      qa[mt] = *(const short8*)&qS[(mt * 16 + lr) * 40 + lg * 8];
#pragma unroll
    for (int jt = 0; jt < 4; ++jt)
      kb[jt] = *(const short8*)&kS[(jt * 16 + lr) * 40 + lg * 8];
#pragma unroll
    for (int mt = 0; mt < 4; ++mt)
#pragma unroll
      for (int jt = 0; jt < 4; ++jt)
        s[mt][jt] = __builtin_amdgcn_mfma_f32_16x16x32_bf16(qa[mt], kb[jt], (f32x4){0.f, 0.f, 0.f, 0.f}, 0, 0, 0);
  }
  {
    const float* rpe_h  = rpe + w * 4096;
    const float* mask_w = mask + (bid & 1023) * 4096;
#pragma unroll
    for (int mt = 0; mt < 4; ++mt)
#pragma unroll
      for (int r = 0; r < 4; ++r) {
        int i = mt * 16 + lg * 4 + r;
        const float* rp = rpe_h + i * 64 + lr;
        const float* mp = mask_w + i * 64 + lr;
        float v0 = s[mt][0][r] + rp[0]  + mp[0];
        float v1 = s[mt][1][r] + rp[16] + mp[16];
        float v2 = s[mt][2][r] + rp[32] + mp[32];
        float v3 = s[mt][3][r] + rp[48] + mp[48];
        float mx = fmaxf(fmaxf(v0, v1), fmaxf(v2, v3));
#pragma unroll
        for (int d = 1; d < 16; d <<= 1) mx = fmaxf(mx, __shfl_xor(mx, d, 64));
        v0 = __expf(v0 - mx); v1 = __expf(v1 - mx);
        v2 = __expf(v2 - mx); v3 = __expf(v3 - mx);
        float sum = v0 + v1 + v2 + v3;
#pragma unroll
        for (int d = 1; d < 16; d <<= 1) sum += __shfl_xor(sum, d, 64);
        float inv = 1.0f / sum;
        pS[i * 72 + lr]      = f2bf(v0 * inv);
        pS[i * 72 + lr + 16] = f2bf(v1 * inv);
        pS[i * 72 + lr + 32] = f2bf(v2 * inv);
        pS[i * 72 + lr + 48] = f2bf(v3 * inv);
      }
  }

  // ---- Phase 4: O = P @ v  (64x64 @ 64x32)
  f32x4 oacc[4][2];
#pragma unroll
  for (int mt = 0; mt < 4; ++mt)
#pragma unroll
    for (int nt = 0; nt < 2; ++nt)
      oacc[mt][nt] = (f32x4){0.f, 0.f, 0.f, 0.f};
#pragma unroll
  for (int ks = 0; ks < 2; ++ks) {
    short8 pa[4], vb[2];
#pragma unroll
    for (int mt = 0; mt < 4; ++mt)
      pa[mt] = *(const short8*)&pS[(mt * 16 + lr) * 72 + ks * 32 + lg * 8];
#pragma unroll
    for (int nt = 0; nt < 2; ++nt)
      vb[nt] = *(const short8*)&vS[(nt * 16 + lr) * 72 + ks * 32 + lg * 8];
#pragma unroll
    for (int mt = 0; mt < 4; ++mt)
#pragma unroll
      for (int nt = 0; nt < 2; ++nt)
        oacc[mt][nt] = __builtin_amdgcn_mfma_f32_16x16x32_bf16(pa[mt], vb[nt], oacc[mt][nt], 0, 0, 0);
  }
  // write attn-out into dead x-buf as O_all[tok][264], ch = head*32 + d
#pragma unroll
  for (int mt = 0; mt < 4; ++mt)
#pragma unroll
    for (int nt = 0; nt < 2; ++nt)
#pragma unroll
      for (int r = 0; r < 4; ++r) {
        int tok = mt * 16 + lg * 4 + r;
        int ch  = w * 32 + nt * 16 + lr;
        lds[tok * 264 + ch] = f2bf(oacc[mt][nt][r]);
      }
  __syncthreads();   // B2: O_all complete

  // ---- Phase 5: out = O_all @ proj_w^T + proj_b ; wave w owns cols [w*32, w*32+32)
  f32x4 pacc[4][2];
#pragma unroll
  for (int mt = 0; mt < 4; ++mt)
#pragma unroll
    for (int nt = 0; nt < 2; ++nt)
      pacc[mt][nt] = (f32x4){0.f, 0.f, 0.f, 0.f};
#pragma unroll
  for (int ks = 0; ks < 8; ++ks) {
    short8 a[4], b[2];
#pragma unroll
    for (int mt = 0; mt < 4; ++mt)
      a[mt] = *(const short8*)&lds[(mt * 16 + lr) * 264 + ks * 32 + lg * 8];
#pragma unroll
    for (int nt = 0; nt < 2; ++nt)
      b[nt] = *(const short8*)&proj_wb[(w * 32 + nt * 16 + lr) * 256 + ks * 32 + lg * 8];
#pragma unroll
    for (int mt = 0; mt < 4; ++mt)
#pragma unroll
      for (int nt = 0; nt < 2; ++nt)
        pacc[mt][nt] = __builtin_amdgcn_mfma_f32_16x16x32_bf16(a[mt], b[nt], pacc[mt][nt], 0, 0, 0);
  }
  {
    float* og = out + (size_t)bid * (NTOK * DIM);
#pragma unroll
    for (int nt = 0; nt < 2; ++nt) {
      float pb = proj_b[w * 32 + nt * 16 + lr];
#pragma unroll
      for (int mt = 0; mt < 4; ++mt)
#pragma unroll
        for (int r = 0; r < 4; ++r) {
          int tok = mt * 16 + lg * 4 + r;
          int ch  = w * 32 + nt * 16 + lr;
          og[tok * 256 + ch] = pacc[mt][nt][r] + pb;
        }
    }
  }
}

extern "C" void kernel_launch(void* const* d_in, const int* in_sizes, int n_in,
                              void* d_out, int out_size, void* d_ws, size_t ws_size,
                              hipStream_t stream) {
  (void)in_sizes; (void)n_in; (void)out_size; (void)ws_size;
  const float* x      = (const float*)d_in[0];
  const float* mask   = (const float*)d_in[1];
  const float* qkv_w  = (const float*)d_in[2];
  const float* qkv_b  = (const float*)d_in[3];
  const float* proj_w = (const float*)d_in[4];
  const float* proj_b = (const float*)d_in[5];
  const float* rpb    = (const float*)d_in[6];
  const int*   rel    = (const int*)d_in[7];

  unsigned short* qkv_wb  = (unsigned short*)d_ws;                       // 393216 B
  unsigned short* proj_wb = (unsigned short*)((char*)d_ws + 393216);     // 131072 B
  float*          rpe     = (float*)((char*)d_ws + 524288);              // 131072 B
  float*          out     = (float*)d_out;

  cvt_weights_kernel<<<dim3(1024), dim3(256), 0, stream>>>(qkv_w, proj_w, qkv_wb, proj_wb);
  build_rpe_kernel<<<dim3(128), dim3(256), 0, stream>>>(rpb, rel, rpe);
  win_attn_kernel<<<dim3(4096), dim3(512), 0, stream>>>(x, mask, qkv_wb, qkv_b,
                                                        proj_wb, proj_b, rpe, out);
}